// Round 8
// baseline (39.510 us; speedup 1.0000x reference)
//
#include <hip/hip_runtime.h>

#define POOL 7
#define NPTS 49

typedef float f4 __attribute__((ext_vector_type(4)));

__device__ __forceinline__ f4 ld4(const float* p) { return *(const f4*)p; }

__device__ __forceinline__ int roi_level(float dy, float dx) {
    // matches jnp: log2(sqrt(max(h*w,0)) / 0.21875 + 1e-8), round half-even
    const float rl = log2f(sqrtf(fmaxf(dy * dx, 0.0f)) / 0.21875f + 1e-8f);
    int lvl = 4 + (int)rintf(rl);
    return lvl < 3 ? 3 : (lvl > 6 ? 6 : lvl);
}

// Single-block scheduler: counting-sort ROIs by (batch, level, y-octant),
// then emit sched[bid] = roi such that each XCD (bid % 8, empirical mapping)
// receives the k-th contiguous eighth of EVERY (batch,level) group:
// balanced work composition per XCD + y-contiguous locality windows.
__global__ __launch_bounds__(1024) void sched_kernel(
    const float* __restrict__ props, int* __restrict__ sched, int BN, int N)
{
    __shared__ unsigned char keys[2048];
    __shared__ int hist[32];
    __shared__ int bbase[32];     // per-bucket scatter cursor (sorted pos)
    __shared__ int G[5];          // group starts in sorted order
    __shared__ int q_[4], r_[4];  // per-group split-by-8 geometry
    __shared__ int cnt[8];        // per-section totals
    __shared__ int goff[4][8];    // offset of group g inside section k
    __shared__ int cumHole[9], cumExtra[9];

    const int tid = threadIdx.x;
    if (tid < 32) hist[tid] = 0;
    __syncthreads();

    for (int r = tid; r < BN; r += 1024) {
        const f4 p = ld4(props + (size_t)r * 4);
        const int lvl = roi_level(p.z - p.x, p.w - p.y);
        int lg = lvl - 3; lg = lg < 0 ? 0 : (lg > 1 ? 1 : lg);  // data hits {3,4}
        const float yc = 0.5f * (p.x + p.z);
        int oct = (int)(yc * 8.0f);
        oct = oct < 0 ? 0 : (oct > 7 ? 7 : oct);
        const int bb = r >= N ? 1 : 0;
        const int k = ((bb << 1) | lg) * 8 + oct;
        keys[r] = (unsigned char)k;
        atomicAdd(&hist[k], 1);
    }
    __syncthreads();

    if (tid == 0) {
        int acc = 0;
        for (int i = 0; i < 32; ++i) { bbase[i] = acc; acc += hist[i]; }
        for (int g = 0; g < 4; ++g) G[g] = bbase[g * 8];
        G[4] = BN;
        for (int g = 0; g < 4; ++g) {
            const int Sg = G[g + 1] - G[g];
            q_[g] = Sg >> 3; r_[g] = Sg & 7;
        }
        for (int k = 0; k < 8; ++k) {
            int a2 = 0;
            for (int g = 0; g < 4; ++g) {
                goff[g][k] = a2;
                a2 += q_[g] + (k < r_[g] ? 1 : 0);
            }
            cnt[k] = a2;
        }
        const int nslot = BN >> 3;
        int ch = 0, ce = 0;
        for (int k = 0; k < 8; ++k) {
            cumHole[k] = ch; cumExtra[k] = ce;
            ch += cnt[k] < nslot ? nslot - cnt[k] : 0;
            ce += cnt[k] > nslot ? cnt[k] - nslot : 0;
        }
        cumHole[8] = ch; cumExtra[8] = ce;
    }
    __syncthreads();

    const int nslot = BN >> 3;   // 250 (BN=2000)
    for (int r = tid; r < BN; r += 1024) {
        const int k = keys[r];
        const int g = k >> 3;
        const int p_old = atomicAdd(&bbase[k], 1);   // global sorted position
        const int rg = p_old - G[g];                 // rank within group
        const int qg = q_[g], rr = r_[g];
        int sec, j;
        if (rg < rr * (qg + 1)) { sec = rg / (qg + 1); j = rg - sec * (qg + 1); }
        else { const int t = rg - rr * (qg + 1); sec = rr + t / qg; j = t - (sec - rr) * qg; }
        const int o = goff[g][sec] + j;              // ordinal within section
        int bid;
        if (o < nslot) {
            bid = o * 8 + sec;
        } else {                                     // extra -> matched hole
            const int e = cumExtra[sec] + (o - nslot);
            int hk = 0;
            while (!(e >= cumHole[hk] && e < cumHole[hk + 1])) ++hk;
            const int ho = cnt[hk] + (e - cumHole[hk]);
            bid = ho * 8 + hk;
        }
        sched[bid] = r;
    }
}

// One block per schedule slot. 256 threads = 4 point-lanes x 64 channel-lanes.
// Stores software-pipelined one iteration behind the loads (round-7, neutral
// but harmless). roi comes straight from sched[blockIdx].
__global__ __launch_bounds__(256) void roialign_kernel(
    const float* __restrict__ p3, const float* __restrict__ p4,
    const float* __restrict__ p5, const float* __restrict__ p6,
    const float* __restrict__ props, const int* __restrict__ sched,
    float* __restrict__ out, int B, int N, int C)
{
    const int roi = sched[blockIdx.x];
    const int b   = roi >= N ? 1 : 0;

    const f4 pv = ld4(props + (size_t)roi * 4);
    const float y1 = pv.x, x1 = pv.y, y2 = pv.z, x2 = pv.w;
    const float dy = y2 - y1, dx = x2 - x1;

    const int lvl = roi_level(dy, dx);
    const float* f;
    int H;
    if      (lvl == 3) { f = p3; H = 128; }
    else if (lvl == 4) { f = p4; H = 64;  }
    else if (lvl == 5) { f = p5; H = 32;  }
    else               { f = p6; H = 16;  }
    const int W = H;
    const float hm1 = (float)(H - 1);
    const float* fb = f + (size_t)b * H * W * C;

    const int tid = threadIdx.x;
    const int pl  = tid >> 6;             // point lane 0..3
    const int cg  = (tid & 63) << 2;      // channel offset (float4)

    const int obase = roi * NPTS * C + cg;

    auto calc = [&](int p, int& o00, int& o01, int& o10, int& o11,
                    float& fx, float& fy) {
        const int py = p / POOL;
        const int px = p - py * POOL;
        const float ys = (y1 + (float)py * (1.0f / (POOL - 1)) * dy) * hm1;
        const float xs = (x1 + (float)px * (1.0f / (POOL - 1)) * dx) * hm1;
        const float y0f = floorf(ys);
        const float x0f = floorf(xs);
        fy = ys - y0f;
        fx = xs - x0f;
        int yA = (int)y0f; yA = yA < 0 ? 0 : (yA > H - 1 ? H - 1 : yA);
        int yB = yA + 1;   yB = yB > H - 1 ? H - 1 : yB;
        int xA = (int)x0f; xA = xA < 0 ? 0 : (xA > W - 1 ? W - 1 : xA);
        int xB = xA + 1;   xB = xB > W - 1 ? W - 1 : xB;
        const int rA = yA * W, rB = yB * W;
        o00 = (rA + xA) * C + cg;
        o01 = (rA + xB) * C + cg;
        o10 = (rB + xA) * C + cg;
        o11 = (rB + xB) * C + cg;
    };

    f4 oa_p, ob_p;
    int pa_p = -1, pb_p = -1;

    #pragma unroll
    for (int p0 = 0; p0 < 48; p0 += 8) {
        const int pa = p0 + pl;   // <= 43
        const int pb = pa + 4;    // <= 47
        int a00, a01, a10, a11, b00, b01, b10, b11;
        float afx, afy, bfx, bfy;
        calc(pa, a00, a01, a10, a11, afx, afy);
        calc(pb, b00, b01, b10, b11, bfx, bfy);

        const f4 va00 = ld4(fb + a00), va01 = ld4(fb + a01);
        const f4 va10 = ld4(fb + a10), va11 = ld4(fb + a11);
        const f4 vb00 = ld4(fb + b00), vb01 = ld4(fb + b01);
        const f4 vb10 = ld4(fb + b10), vb11 = ld4(fb + b11);

        if (pa_p >= 0) {
            __builtin_nontemporal_store(oa_p, (f4*)(out + obase + pa_p * C));
            __builtin_nontemporal_store(ob_p, (f4*)(out + obase + pb_p * C));
        }

        const f4 ta = va00 + afx * (va01 - va00);
        const f4 ba = va10 + afx * (va11 - va10);
        const f4 oa = ta + afy * (ba - ta);
        const f4 tb = vb00 + bfx * (vb01 - vb00);
        const f4 bb = vb10 + bfx * (vb11 - vb10);
        const f4 ob = tb + bfy * (bb - tb);

        oa_p = oa; ob_p = ob; pa_p = pa; pb_p = pb;
    }

    if (pl == 0) {
        int o00, o01, o10, o11;
        float fx, fy;
        calc(48, o00, o01, o10, o11, fx, fy);
        const f4 v00 = ld4(fb + o00), v01 = ld4(fb + o01);
        const f4 v10 = ld4(fb + o10), v11 = ld4(fb + o11);

        __builtin_nontemporal_store(oa_p, (f4*)(out + obase + pa_p * C));
        __builtin_nontemporal_store(ob_p, (f4*)(out + obase + pb_p * C));

        const f4 t  = v00 + fx * (v01 - v00);
        const f4 bo = v10 + fx * (v11 - v10);
        const f4 o  = t + fy * (bo - t);
        __builtin_nontemporal_store(o, (f4*)(out + obase + 48 * C));
    } else {
        __builtin_nontemporal_store(oa_p, (f4*)(out + obase + pa_p * C));
        __builtin_nontemporal_store(ob_p, (f4*)(out + obase + pb_p * C));
    }
}

extern "C" void kernel_launch(void* const* d_in, const int* in_sizes, int n_in,
                              void* d_out, int out_size, void* d_ws, size_t ws_size,
                              hipStream_t stream) {
    (void)ws_size; (void)n_in; (void)out_size;

    const float* p3 = (const float*)d_in[0];
    const float* p4 = (const float*)d_in[1];
    const float* p5 = (const float*)d_in[2];
    const float* p6 = (const float*)d_in[3];
    const float* props = (const float*)d_in[4];
    float* out = (float*)d_out;
    int* sched = (int*)d_ws;

    const int B = 2;
    const int N = in_sizes[4] / (B * 4);          // 1000
    const int C = in_sizes[0] / (B * 128 * 128);  // 256
    const int BN = B * N;

    sched_kernel<<<1, 1024, 0, stream>>>(props, sched, BN, N);
    roialign_kernel<<<BN, 256, 0, stream>>>(p3, p4, p5, p6, props, sched,
                                            out, B, N, C);
}

// Round 9
// 32.827 us; speedup vs baseline: 1.2036x; 1.2036x over previous
//
#include <hip/hip_runtime.h>

#define POOL 7
#define NPTS 49

typedef float f4 __attribute__((ext_vector_type(4)));

__device__ __forceinline__ f4 ld4(const float* p) { return *(const f4*)p; }

__device__ __forceinline__ int roi_level(float dy, float dx) {
    // matches jnp: log2(sqrt(max(h*w,0)) / 0.21875 + 1e-8), round half-even
    const float rl = log2f(sqrtf(fmaxf(dy * dx, 0.0f)) / 0.21875f + 1e-8f);
    int lvl = 4 + (int)rintf(rl);
    return lvl < 3 ? 3 : (lvl > 6 ? 6 : lvl);
}

__device__ __forceinline__ int bucket_key(const float* props, int r, int N) {
    const f4 p = ld4(props + (size_t)r * 4);
    const int lvl = roi_level(p.z - p.x, p.w - p.y);
    const float yc = 0.5f * (p.x + p.z);
    int oct = (int)(yc * 8.0f);
    oct = oct < 0 ? 0 : (oct > 7 ? 7 : oct);
    int lg = lvl - 3; lg = lg < 0 ? 0 : (lg > 1 ? 1 : lg);  // data only hits {3,4}
    const int b = r >= N ? 1 : 0;
    return ((b << 1) | lg) * 8 + oct;   // [0,32)
}

// Single-block counting sort: order[] gets ROI indices grouped by
// (batch, level, y-octant) -> spatially/level coherent chunks. (round-3 proven)
__global__ __launch_bounds__(1024) void bucket_kernel(
    const float* __restrict__ props, int* __restrict__ order, int BN, int N)
{
    __shared__ int hist[32];
    __shared__ int offs[32];
    const int tid = threadIdx.x;
    if (tid < 32) hist[tid] = 0;
    __syncthreads();
    for (int r = tid; r < BN; r += 1024)
        atomicAdd(&hist[bucket_key(props, r, N)], 1);
    __syncthreads();
    if (tid == 0) {
        int acc = 0;
        for (int i = 0; i < 32; ++i) { offs[i] = acc; acc += hist[i]; }
    }
    __syncthreads();
    for (int r = tid; r < BN; r += 1024) {
        const int k = bucket_key(props, r, N);
        const int pos = atomicAdd(&offs[k], 1);
        order[pos] = r;
    }
}

// One block per sorted ROI slot. 256 threads = 4 point-lanes x 64 channel-lanes.
// Depth-2 software pipeline: iteration i+1's 8 corner loads are issued before
// iteration i's results are consumed -> compiler waits vmcnt(8), 16 loads in
// flight per wave -> iteration (and store-issue) throughput doubles.
__global__ __launch_bounds__(256) void roialign_kernel(
    const float* __restrict__ p3, const float* __restrict__ p4,
    const float* __restrict__ p5, const float* __restrict__ p6,
    const float* __restrict__ props, const int* __restrict__ order,
    float* __restrict__ out, int B, int N, int C, int nwg)
{
    // bijective chunked XCD swizzle (m204)
    const int s   = blockIdx.x;
    const int q   = nwg >> 3, rr = nwg & 7;
    const int xcd = s & 7, idx = s >> 3;
    const int s2  = (xcd < rr ? xcd * (q + 1) : rr * (q + 1) + (xcd - rr) * q) + idx;
    const int roi = order[s2];
    const int b   = roi >= N ? 1 : 0;

    const f4 pv = ld4(props + (size_t)roi * 4);
    const float y1 = pv.x, x1 = pv.y, y2 = pv.z, x2 = pv.w;
    const float dy = y2 - y1, dx = x2 - x1;

    const int lvl = roi_level(dy, dx);
    const float* f;
    int H;
    if      (lvl == 3) { f = p3; H = 128; }
    else if (lvl == 4) { f = p4; H = 64;  }
    else if (lvl == 5) { f = p5; H = 32;  }
    else               { f = p6; H = 16;  }
    const int W = H;
    const float hm1 = (float)(H - 1);
    const float* fb = f + (size_t)b * H * W * C;

    const int tid = threadIdx.x;
    const int pl  = tid >> 6;             // point lane 0..3
    const int cg  = (tid & 63) << 2;      // channel offset (float4)

    const int obase = roi * NPTS * C + cg;

    auto calc = [&](int p, int& o00, int& o01, int& o10, int& o11,
                    float& fx, float& fy) {
        const int py = p / POOL;
        const int px = p - py * POOL;
        const float ys = (y1 + (float)py * (1.0f / (POOL - 1)) * dy) * hm1;
        const float xs = (x1 + (float)px * (1.0f / (POOL - 1)) * dx) * hm1;
        const float y0f = floorf(ys);
        const float x0f = floorf(xs);
        fy = ys - y0f;
        fx = xs - x0f;
        int yA = (int)y0f; yA = yA < 0 ? 0 : (yA > H - 1 ? H - 1 : yA);
        int yB = yA + 1;   yB = yB > H - 1 ? H - 1 : yB;
        int xA = (int)x0f; xA = xA < 0 ? 0 : (xA > W - 1 ? W - 1 : xA);
        int xB = xA + 1;   xB = xB > W - 1 ? W - 1 : xB;
        const int rA = yA * W, rB = yB * W;
        o00 = (rA + xA) * C + cg;
        o01 = (rA + xB) * C + cg;
        o10 = (rB + xA) * C + cg;
        o11 = (rB + xB) * C + cg;
    };

    // explicit named register sets (no runtime-indexed arrays -> no scratch)
    f4 A_v0, A_v1, A_v2, A_v3, A_v4, A_v5, A_v6, A_v7;
    f4 B_v0, B_v1, B_v2, B_v3, B_v4, B_v5, B_v6, B_v7;
    float A_fxa, A_fya, A_fxb, A_fyb, B_fxa, B_fya, B_fxb, B_fyb;
    int A_pa, A_pb, B_pa, B_pb;

#define STAGE(S, P0)                                                        \
    {                                                                       \
        const int pa = (P0) + pl, pb = pa + 4;                              \
        S##_pa = pa; S##_pb = pb;                                           \
        int a00, a01, a10, a11, b00, b01, b10, b11;                         \
        calc(pa, a00, a01, a10, a11, S##_fxa, S##_fya);                     \
        calc(pb, b00, b01, b10, b11, S##_fxb, S##_fyb);                     \
        S##_v0 = ld4(fb + a00); S##_v1 = ld4(fb + a01);                     \
        S##_v2 = ld4(fb + a10); S##_v3 = ld4(fb + a11);                     \
        S##_v4 = ld4(fb + b00); S##_v5 = ld4(fb + b01);                     \
        S##_v6 = ld4(fb + b10); S##_v7 = ld4(fb + b11);                     \
    }

#define EMIT(S)                                                             \
    {                                                                       \
        const f4 ta = S##_v0 + S##_fxa * (S##_v1 - S##_v0);                 \
        const f4 ba = S##_v2 + S##_fxa * (S##_v3 - S##_v2);                 \
        const f4 oa = ta + S##_fya * (ba - ta);                             \
        const f4 tb = S##_v4 + S##_fxb * (S##_v5 - S##_v4);                 \
        const f4 bb = S##_v6 + S##_fxb * (S##_v7 - S##_v6);                 \
        const f4 ob = tb + S##_fyb * (bb - tb);                             \
        __builtin_nontemporal_store(oa, (f4*)(out + obase + S##_pa * C));   \
        __builtin_nontemporal_store(ob, (f4*)(out + obase + S##_pb * C));   \
    }

    STAGE(A, 0)
    STAGE(B, 8)  EMIT(A)
    STAGE(A, 16) EMIT(B)
    STAGE(B, 24) EMIT(A)
    STAGE(A, 32) EMIT(B)
    STAGE(B, 40) EMIT(A)
    EMIT(B)

#undef STAGE
#undef EMIT

    // tail: point 48 (point-lane 0 only)
    if (pl == 0) {
        int o00, o01, o10, o11;
        float fx, fy;
        calc(48, o00, o01, o10, o11, fx, fy);
        const f4 v00 = ld4(fb + o00), v01 = ld4(fb + o01);
        const f4 v10 = ld4(fb + o10), v11 = ld4(fb + o11);
        const f4 t  = v00 + fx * (v01 - v00);
        const f4 bo = v10 + fx * (v11 - v10);
        const f4 o  = t + fy * (bo - t);
        __builtin_nontemporal_store(o, (f4*)(out + obase + 48 * C));
    }
}

extern "C" void kernel_launch(void* const* d_in, const int* in_sizes, int n_in,
                              void* d_out, int out_size, void* d_ws, size_t ws_size,
                              hipStream_t stream) {
    (void)ws_size; (void)n_in; (void)out_size;

    const float* p3 = (const float*)d_in[0];
    const float* p4 = (const float*)d_in[1];
    const float* p5 = (const float*)d_in[2];
    const float* p6 = (const float*)d_in[3];
    const float* props = (const float*)d_in[4];
    float* out = (float*)d_out;
    int* order = (int*)d_ws;

    const int B = 2;
    const int N = in_sizes[4] / (B * 4);          // 1000
    const int C = in_sizes[0] / (B * 128 * 128);  // 256
    const int BN = B * N;

    bucket_kernel<<<1, 1024, 0, stream>>>(props, order, BN, N);
    roialign_kernel<<<BN, 256, 0, stream>>>(p3, p4, p5, p6, props, order,
                                            out, B, N, C, BN);
}